// Round 6
// baseline (467.237 us; speedup 1.0000x reference)
//
#include <hip/hip_runtime.h>
#include <hip/hip_fp16.h>

#define B 32
#define NW2V 300
#define NR 200
#define NBLK 256          // chunks for count/scatter passes
#define NB_C 2048         // coarse bins: 8 subj-tiles x 256 obj-windows
#define MAXNB 2048        // LDS histogram capacity
#define CS_THREADS 1024   // block size for count/scatter (occupancy)
#define HOP_PB 1024       // hop blocks per partition (grid-strided if short)

// Coarse sort key: (subj-tile, obj-window). subj-tile = subj>>16 gives 8
// tiles of 65536 entities = 4 MB of xT each == one XCD's L2. obj>>11 < 256
// windows. Fine key = obj & 2047 -> full (tile, obj) ordering.

// r_T[j][b] = bias[j] + sum_k q[b][k] * W[k][j]   -> [N_R, B] layout, fp32
__global__ void compute_r_kernel(const float* __restrict__ q,
                                 const float* __restrict__ W,
                                 const float* __restrict__ bias,
                                 float* __restrict__ rT) {
    int tid = blockIdx.x * blockDim.x + threadIdx.x;
    if (tid >= NR * B) return;
    int b = tid & (B - 1);
    int j = tid >> 5;
    float acc = bias[j];
    for (int k = 0; k < NW2V; ++k)
        acc += q[b * NW2V + k] * W[k * NR + j];
    rT[j * B + b] = acc;
}

// x [B, N_E] f32 -> xT [N_E, B] f16
__global__ void transpose_in_kernel(const float* __restrict__ x,
                                    __half* __restrict__ xT, int n_e) {
    __shared__ float tile[64][33];
    int e0 = blockIdx.x * 64;
    for (int p = 0; p < 8; ++p) {
        int idx = p * 256 + threadIdx.x;
        int b = idx >> 6, e = idx & 63;
        if (e0 + e < n_e) tile[e][b] = x[(size_t)b * n_e + e0 + e];
    }
    __syncthreads();
    for (int p = 0; p < 8; ++p) {
        int idx = p * 256 + threadIdx.x;
        int b = idx & 31, e = idx >> 5;
        if (e0 + e < n_e) xT[(size_t)(e0 + e) * B + b] = __float2half(tile[e][b]);
    }
}

// xT [N_E, B] f16 -> out [B, N_E] f32
__global__ void transpose_out_kernel(const __half* __restrict__ xT,
                                     float* __restrict__ out, int n_e) {
    __shared__ float tile[64][33];
    int e0 = blockIdx.x * 64;
    for (int p = 0; p < 8; ++p) {
        int idx = p * 256 + threadIdx.x;
        int b = idx & 31, e = idx >> 5;
        if (e0 + e < n_e) tile[e][b] = __half2float(xT[(size_t)(e0 + e) * B + b]);
    }
    __syncthreads();
    for (int p = 0; p < 8; ++p) {
        int idx = p * 256 + threadIdx.x;
        int b = idx >> 6, e = idx & 63;
        if (e0 + e < n_e) out[(size_t)b * n_e + e0 + e] = tile[e][b];
    }
}

// ---- two-level sort of triples by (subj-tile, obj) ----

__global__ void count_kernel(const int* __restrict__ subj,
                             const int* __restrict__ obj,
                             int* __restrict__ hist_bb, int n_t, int chunk) {
    __shared__ int h[MAXNB];
    for (int i = threadIdx.x; i < NB_C; i += CS_THREADS) h[i] = 0;
    __syncthreads();
    int t0 = blockIdx.x * chunk;
    int t1 = min(t0 + chunk, n_t);
    for (int t = t0 + threadIdx.x; t < t1; t += CS_THREADS) {
        int bin = ((subj[t] >> 16) << 8) | (obj[t] >> 11);
        atomicAdd(&h[bin], 1);
    }
    __syncthreads();
    for (int i = threadIdx.x; i < NB_C; i += CS_THREADS)
        hist_bb[(size_t)i * NBLK + blockIdx.x] = h[i];
}

__global__ void block_reduce_kernel(const int* __restrict__ vals,
                                    int* __restrict__ blockSums, int len) {
    __shared__ int s[256];
    int i = blockIdx.x * 256 + threadIdx.x;
    s[threadIdx.x] = (i < len) ? vals[i] : 0;
    __syncthreads();
    for (int off = 128; off > 0; off >>= 1) {
        if (threadIdx.x < off) s[threadIdx.x] += s[threadIdx.x + off];
        __syncthreads();
    }
    if (threadIdx.x == 0) blockSums[blockIdx.x] = s[0];
}

__global__ void scan_blocksums_kernel(int* __restrict__ blockSums, int nb) {
    __shared__ int s[256];
    int t = threadIdx.x;
    int local[8];
    int run = 0;
    for (int c = 0; c < 8; ++c) {
        int j = t * 8 + c;
        run += (j < nb) ? blockSums[j] : 0;
        local[c] = run;
    }
    s[t] = run;
    __syncthreads();
    for (int off = 1; off < 256; off <<= 1) {
        int v = (t >= off) ? s[t - off] : 0;
        __syncthreads();
        s[t] += v;
        __syncthreads();
    }
    int threadExcl = s[t] - run;
    for (int c = 0; c < 8; ++c) {
        int j = t * 8 + c;
        if (j < nb) blockSums[j] = threadExcl + (c == 0 ? 0 : local[c - 1]);
    }
}

__global__ void scan_apply_kernel(const int* __restrict__ vals,
                                  const int* __restrict__ blockSums,
                                  int* __restrict__ out, int len) {
    __shared__ int s[256];
    int t = threadIdx.x;
    int i = blockIdx.x * 256 + t;
    int c = (i < len) ? vals[i] : 0;
    s[t] = c;
    __syncthreads();
    for (int off = 1; off < 256; off <<= 1) {
        int v = (t >= off) ? s[t - off] : 0;
        __syncthreads();
        s[t] += v;
        __syncthreads();
    }
    if (i < len) out[i] = blockSums[blockIdx.x] + s[t] - c;
}

// coarse scatter into (tile, obj-window) buckets
__global__ void scatter8_kernel(const int* __restrict__ subj,
                                const int* __restrict__ rel,
                                const int* __restrict__ obj,
                                const int* __restrict__ base_bb,
                                uint2* __restrict__ packed2,
                                int n_t, int chunk) {
    __shared__ int h[MAXNB];
    __shared__ int sbase[MAXNB];
    for (int i = threadIdx.x; i < NB_C; i += CS_THREADS) {
        h[i] = 0;
        sbase[i] = base_bb[(size_t)i * NBLK + blockIdx.x];
    }
    __syncthreads();
    int t0 = blockIdx.x * chunk;
    int t1 = min(t0 + chunk, n_t);
    for (int t = t0 + threadIdx.x; t < t1; t += CS_THREADS) {
        int o = obj[t];
        int bin = ((subj[t] >> 16) << 8) | (o >> 11);
        int rank = atomicAdd(&h[bin], 1);
        packed2[sbase[bin] + rank] = make_uint2(
            (unsigned)subj[t] | ((unsigned)rel[t] << 19), (unsigned)o);
    }
}

// fine counting sort by obj&2047 within each coarse bucket -> full
// (tile, obj) order. 2048 fine bins; 256 threads own 8 bins each for the scan.
__global__ void fine_sort_kernel(const uint2* __restrict__ in,
                                 uint2* __restrict__ outp,
                                 const int* __restrict__ base_bb,
                                 int n_t) {
    __shared__ int cnt[2048];
    __shared__ int cur[2048];
    __shared__ int ts[256];
    int bin = blockIdx.x;
    int beg = base_bb[(size_t)bin * NBLK];
    int end = (bin + 1 < NB_C) ? base_bb[(size_t)(bin + 1) * NBLK] : n_t;
    int t = threadIdx.x;
    for (int k = t; k < 2048; k += 256) cnt[k] = 0;
    __syncthreads();
    for (int i = beg + t; i < end; i += 256)
        atomicAdd(&cnt[in[i].y & 2047], 1);
    __syncthreads();
    int loc[8];
    int run = 0;
    for (int c = 0; c < 8; ++c) { run += cnt[t * 8 + c]; loc[c] = run; }
    ts[t] = run;
    __syncthreads();
    for (int off = 1; off < 256; off <<= 1) {
        int v = (t >= off) ? ts[t - off] : 0;
        __syncthreads();
        ts[t] += v;
        __syncthreads();
    }
    int excl = ts[t] - run;
    for (int c = 0; c < 8; ++c)
        cur[t * 8 + c] = beg + excl + (c == 0 ? 0 : loc[c - 1]);
    __syncthreads();
    for (int i = beg + t; i < end; i += 256) {
        uint2 e = in[i];
        int pos = atomicAdd(&cur[e.y & 2047], 1);
        outp[pos] = e;
    }
}

// Flat hop over partition-sorted triples. Partition p (subj-tile p) is
// processed ONLY by blocks with blockIdx&7 == p, which round-robin dispatch
// places on XCD p -> every gather hits a 4 MB xT slice resident in that
// XCD's L2. Grid-strided over the partition so any partition size is safe.
// Merge logic unchanged: runs contiguous within partition (full tile,obj
// sort); run closes are fire-and-forget pk-f16 atomics.
__global__ void hop_merge_kernel(const __half2* __restrict__ xT2,
                                 const float2* __restrict__ rT2,
                                 __half2* __restrict__ outT2,
                                 const uint2* __restrict__ sorted2,
                                 const int* __restrict__ base_bb,
                                 const int* __restrict__ n_hop,
                                 int hop, int n_e, int n_t) {
    int tid = threadIdx.x;
    if (*n_hop < hop) {               // degenerate: identity copy
        long total = (long)n_e * 16;
        for (long i = (long)blockIdx.x * 256 + tid; i < total;
             i += (long)gridDim.x * 256)
            outT2[i] = xT2[i];
        return;
    }
    int p = blockIdx.x & 7;           // partition == XCD (round-robin)
    int ib = blockIdx.x >> 3;
    int pbeg = base_bb[(size_t)(p << 8) * NBLK];
    int pend = (p == 7) ? n_t : base_bb[(size_t)((p + 1) << 8) * NBLK];

    __shared__ uint2 ent[256];
    int g = tid >> 4, l = tid & 15;
    int e0 = g * 16;

    for (int base = pbeg + (ib << 8); base < pend; base += (HOP_PB << 8)) {
        int cnt = min(256, pend - base);
        __syncthreads();              // ent reuse across grid-stride iters
        ent[tid] = (tid < cnt) ? sorted2[base + tid]
                               : make_uint2(0u, 0xFFFFFFFFu);
        __syncthreads();
        int m = min(16, cnt - e0);    // group-uniform
        if (m > 0) {
            __half2 xh[16];
#pragma unroll
            for (int j = 0; j < 16; ++j) {   // independent gathers in flight
                int s = (int)(ent[e0 + j].x & 0x7FFFF);
                xh[j] = xT2[(size_t)s * 16 + l];
            }
            float a0 = 0.f, a1 = 0.f;
            unsigned cur_o = ent[e0].y;
#pragma unroll
            for (int j = 0; j < 16; ++j) {
                if (j < m) {
                    uint2 e = ent[e0 + j];
                    float2 rf = rT2[(size_t)(e.x >> 19) * 16 + l];  // L1-res
                    float2 xf = __half22float2(xh[j]);
                    if (e.y != cur_o) {      // uniform within 16-lane group
                        unsafeAtomicAdd(&outT2[(size_t)cur_o * 16 + l],
                                        __floats2half2_rn(a0, a1));
                        a0 = 0.f; a1 = 0.f;
                        cur_o = e.y;
                    }
                    a0 += xf.x * rf.x;
                    a1 += xf.y * rf.y;
                }
            }
            unsafeAtomicAdd(&outT2[(size_t)cur_o * 16 + l],
                            __floats2half2_rn(a0, a1));
        }
    }
}

extern "C" void kernel_launch(void* const* d_in, const int* in_sizes, int n_in,
                              void* d_out, int out_size, void* d_ws, size_t ws_size,
                              hipStream_t stream) {
    const float* x    = (const float*)d_in[0];
    const float* q    = (const float*)d_in[1];
    const int*   subj = (const int*)d_in[2];
    const int*   rel  = (const int*)d_in[3];
    const int*   obj  = (const int*)d_in[4];
    const float* W1   = (const float*)d_in[5];
    const float* bb1  = (const float*)d_in[6];
    const float* W2   = (const float*)d_in[7];
    const float* bb2  = (const float*)d_in[8];
    const float* W3   = (const float*)d_in[9];
    const float* bb3  = (const float*)d_in[10];
    const int*   n_hop = (const int*)d_in[11];
    float* out = (float*)d_out;

    const int n_e   = in_sizes[0] / B;        // 500000
    const int n_t   = in_sizes[2];            // 2000000
    const int chunk = (n_t + NBLK - 1) / NBLK;
    const int scanLen = NB_C * NBLK;          // 524288
    const int snb   = (scanLen + 255) / 256;  // 2048 (== scan capacity)

    // ws layout (~102 MB of >=128 MB):
    char* w = (char*)d_ws;
    __half* bufA    = (__half*)w;                     w += 32000000;  // [N_E,B] f16
    __half* bufB    = (__half*)w;                     w += 32000000;  // [N_E,B] f16
    float*  rT      = (float*)w;                      w += 76800;     // 3*[N_R,B]
    int*    hist_bb = (int*)w;                        w += 2097152;   // [NB_C*NBLK]
    int*    base_bb = (int*)w;                        w += 2097152;   // [NB_C*NBLK]
    int*    bsums   = (int*)w;                        w += 16384;     // [snb]
    uint2*  packed2 = (uint2*)w;                      w += 16000000;  // [N_T]
    uint2*  sorted2 = (uint2*)w;                                      // [N_T]

    const int rblocks = (NR * B + 255) / 256;
    compute_r_kernel<<<rblocks, 256, 0, stream>>>(q, W1, bb1, rT + 0 * NR * B);
    compute_r_kernel<<<rblocks, 256, 0, stream>>>(q, W2, bb2, rT + 1 * NR * B);
    compute_r_kernel<<<rblocks, 256, 0, stream>>>(q, W3, bb3, rT + 2 * NR * B);

    const int tblocks = (n_e + 63) / 64;
    transpose_in_kernel<<<tblocks, 256, 0, stream>>>(x, bufA, n_e);

    // --- sort by (subj-tile, obj) (once) ---
    count_kernel<<<NBLK, CS_THREADS, 0, stream>>>(subj, obj, hist_bb, n_t, chunk);
    block_reduce_kernel<<<snb, 256, 0, stream>>>(hist_bb, bsums, scanLen);
    scan_blocksums_kernel<<<1, 256, 0, stream>>>(bsums, snb);
    scan_apply_kernel<<<snb, 256, 0, stream>>>(hist_bb, bsums, base_bb, scanLen);
    scatter8_kernel<<<NBLK, CS_THREADS, 0, stream>>>(subj, rel, obj, base_bb,
                                                     packed2, n_t, chunk);
    fine_sort_kernel<<<NB_C, 256, 0, stream>>>(packed2, sorted2, base_bb, n_t);

    // --- 3 flat hops, XCD-partitioned gathers ---
    const int hblocks = 8 * HOP_PB;           // 8192
    const size_t bytes = (size_t)n_e * B * sizeof(__half);

    hipMemsetAsync(bufB, 0, bytes, stream);
    hop_merge_kernel<<<hblocks, 256, 0, stream>>>((const __half2*)bufA,
        (const float2*)(rT + 0 * NR * B), (__half2*)bufB, sorted2, base_bb,
        n_hop, 1, n_e, n_t);
    hipMemsetAsync(bufA, 0, bytes, stream);
    hop_merge_kernel<<<hblocks, 256, 0, stream>>>((const __half2*)bufB,
        (const float2*)(rT + 1 * NR * B), (__half2*)bufA, sorted2, base_bb,
        n_hop, 2, n_e, n_t);
    hipMemsetAsync(bufB, 0, bytes, stream);
    hop_merge_kernel<<<hblocks, 256, 0, stream>>>((const __half2*)bufA,
        (const float2*)(rT + 2 * NR * B), (__half2*)bufB, sorted2, base_bb,
        n_hop, 3, n_e, n_t);

    transpose_out_kernel<<<tblocks, 256, 0, stream>>>(bufB, out, n_e);
}

// Round 7
// 318.380 us; speedup vs baseline: 1.4675x; 1.4675x over previous
//
#include <hip/hip_runtime.h>
#include <hip/hip_fp16.h>

#define B 32
#define NW2V 300
#define NR 200
#define NBLK 256          // chunks for count/scatter passes
#define MAXNB 2048        // max coarse buckets
#define CS_THREADS 1024   // block size for count/scatter (occupancy: 16 waves/CU)

// r_T[h][j][b] = bias_h[j] + sum_k q[b][k] * W_h[k][j] -> 3 x [N_R, B] fp32.
// All three hops in one launch (blockIdx selects h): saves 2 launch overheads.
__global__ void compute_r3_kernel(const float* __restrict__ q,
                                  const float* __restrict__ W1,
                                  const float* __restrict__ b1,
                                  const float* __restrict__ W2,
                                  const float* __restrict__ b2,
                                  const float* __restrict__ W3,
                                  const float* __restrict__ b3,
                                  float* __restrict__ rT, int rblocks) {
    int h = blockIdx.x / rblocks;
    int tid = (blockIdx.x - h * rblocks) * blockDim.x + threadIdx.x;
    if (tid >= NR * B) return;
    const float* W = (h == 0) ? W1 : (h == 1) ? W2 : W3;
    const float* bias = (h == 0) ? b1 : (h == 1) ? b2 : b3;
    int b = tid & (B - 1);
    int j = tid >> 5;
    float acc = bias[j];
    for (int k = 0; k < NW2V; ++k)
        acc += q[b * NW2V + k] * W[k * NR + j];
    rT[h * NR * B + j * B + b] = acc;
}

// x [B, N_E] f32 -> xT [N_E, B] f16
__global__ void transpose_in_kernel(const float* __restrict__ x,
                                    __half* __restrict__ xT, int n_e) {
    __shared__ float tile[64][33];
    int e0 = blockIdx.x * 64;
    for (int p = 0; p < 8; ++p) {
        int idx = p * 256 + threadIdx.x;
        int b = idx >> 6, e = idx & 63;
        if (e0 + e < n_e) tile[e][b] = x[(size_t)b * n_e + e0 + e];
    }
    __syncthreads();
    for (int p = 0; p < 8; ++p) {
        int idx = p * 256 + threadIdx.x;
        int b = idx & 31, e = idx >> 5;
        if (e0 + e < n_e) xT[(size_t)(e0 + e) * B + b] = __float2half(tile[e][b]);
    }
}

// xT [N_E, B] f16 -> out [B, N_E] f32
__global__ void transpose_out_kernel(const __half* __restrict__ xT,
                                     float* __restrict__ out, int n_e) {
    __shared__ float tile[64][33];
    int e0 = blockIdx.x * 64;
    for (int p = 0; p < 8; ++p) {
        int idx = p * 256 + threadIdx.x;
        int b = idx & 31, e = idx >> 5;
        if (e0 + e < n_e) tile[e][b] = __half2float(xT[(size_t)(e0 + e) * B + b]);
    }
    __syncthreads();
    for (int p = 0; p < 8; ++p) {
        int idx = p * 256 + threadIdx.x;
        int b = idx >> 6, e = idx & 63;
        if (e0 + e < n_e) out[(size_t)b * n_e + e0 + e] = tile[e][b];
    }
}

// ---- two-level sort of triples by obj (shared by all 3 hops) ----

__global__ void count_kernel(const int* __restrict__ obj,
                             int* __restrict__ hist_bb, int n_t, int nb, int chunk) {
    __shared__ int h[MAXNB];
    for (int i = threadIdx.x; i < nb; i += CS_THREADS) h[i] = 0;
    __syncthreads();
    int t0 = blockIdx.x * chunk;
    int t1 = min(t0 + chunk, n_t);
    for (int t = t0 + threadIdx.x; t < t1; t += CS_THREADS)
        atomicAdd(&h[obj[t] >> 8], 1);
    __syncthreads();
    for (int i = threadIdx.x; i < nb; i += CS_THREADS)
        hist_bb[(size_t)i * NBLK + blockIdx.x] = h[i];
}

__global__ void block_reduce_kernel(const int* __restrict__ vals,
                                    int* __restrict__ blockSums, int len) {
    __shared__ int s[256];
    int i = blockIdx.x * 256 + threadIdx.x;
    s[threadIdx.x] = (i < len) ? vals[i] : 0;
    __syncthreads();
    for (int off = 128; off > 0; off >>= 1) {
        if (threadIdx.x < off) s[threadIdx.x] += s[threadIdx.x + off];
        __syncthreads();
    }
    if (threadIdx.x == 0) blockSums[blockIdx.x] = s[0];
}

__global__ void scan_blocksums_kernel(int* __restrict__ blockSums, int nb) {
    __shared__ int s[256];
    int t = threadIdx.x;
    int local[8];
    int run = 0;
    for (int c = 0; c < 8; ++c) {
        int j = t * 8 + c;
        run += (j < nb) ? blockSums[j] : 0;
        local[c] = run;
    }
    s[t] = run;
    __syncthreads();
    for (int off = 1; off < 256; off <<= 1) {
        int v = (t >= off) ? s[t - off] : 0;
        __syncthreads();
        s[t] += v;
        __syncthreads();
    }
    int threadExcl = s[t] - run;
    for (int c = 0; c < 8; ++c) {
        int j = t * 8 + c;
        if (j < nb) blockSums[j] = threadExcl + (c == 0 ? 0 : local[c - 1]);
    }
}

__global__ void scan_apply_kernel(const int* __restrict__ vals,
                                  const int* __restrict__ blockSums,
                                  int* __restrict__ out, int len) {
    __shared__ int s[256];
    int t = threadIdx.x;
    int i = blockIdx.x * 256 + t;
    int c = (i < len) ? vals[i] : 0;
    s[t] = c;
    __syncthreads();
    for (int off = 1; off < 256; off <<= 1) {
        int v = (t >= off) ? s[t - off] : 0;
        __syncthreads();
        s[t] += v;
        __syncthreads();
    }
    if (i < len) out[i] = blockSums[blockIdx.x] + s[t] - c;
}

// coarse scatter into 256-entity buckets
__global__ void scatter8_kernel(const int* __restrict__ subj,
                                const int* __restrict__ rel,
                                const int* __restrict__ obj,
                                const int* __restrict__ base_bb,
                                uint2* __restrict__ packed2,
                                int n_t, int nb, int chunk) {
    __shared__ int h[MAXNB];
    __shared__ int sbase[MAXNB];
    for (int i = threadIdx.x; i < nb; i += CS_THREADS) {
        h[i] = 0;
        sbase[i] = base_bb[(size_t)i * NBLK + blockIdx.x];
    }
    __syncthreads();
    int t0 = blockIdx.x * chunk;
    int t1 = min(t0 + chunk, n_t);
    for (int t = t0 + threadIdx.x; t < t1; t += CS_THREADS) {
        int o = obj[t];
        int bin = o >> 8;
        int rank = atomicAdd(&h[bin], 1);
        packed2[sbase[bin] + rank] = make_uint2(
            (unsigned)subj[t] | ((unsigned)rel[t] << 19), (unsigned)o);
    }
}

// fine counting sort by obj&255 within each bucket -> fully obj-sorted
// (R5 lesson: 1024-thread version is SLOWER -- 16-wave barriers for ~1
// element/thread of work; keep 256.)
__global__ void fine_sort_kernel(const uint2* __restrict__ in,
                                 uint2* __restrict__ outp,
                                 const int* __restrict__ base_bb,
                                 int n_t, int nb) {
    __shared__ int cnt[256];
    __shared__ int cur[256];
    int bin = blockIdx.x;
    int beg = base_bb[(size_t)bin * NBLK];
    int end = (bin + 1 < nb) ? base_bb[(size_t)(bin + 1) * NBLK] : n_t;
    int t = threadIdx.x;
    cnt[t] = 0;
    __syncthreads();
    for (int i = beg + t; i < end; i += 256)
        atomicAdd(&cnt[in[i].y & 255], 1);
    __syncthreads();
    int c = cnt[t];
    __syncthreads();
    for (int off = 1; off < 256; off <<= 1) {
        int v = (t >= off) ? cnt[t - off] : 0;
        __syncthreads();
        cnt[t] += v;
        __syncthreads();
    }
    cur[t] = cnt[t] - c + beg;        // exclusive scan + bucket base
    __syncthreads();
    for (int i = beg + t; i < end; i += 256) {
        uint2 e = in[i];
        int pos = atomicAdd(&cur[e.y & 255], 1);
        outp[pos] = e;
    }
}

// Flat hop over SORTED triples: 16-lane group handles 16 consecutive entries.
// FULLY UNROLLED with compile-time xh[] indices so the per-thread array stays
// in VGPRs. Tail groups padded to 16 with sentinel obj and masked via j<m.
// Session evidence this is the structural optimum:
//  R2: XCD swizzle + asm load-pinning -> neutral-to-negative
//  R3/R4: LDS fp32 accumulation -> 2x slower at equal occupancy
//  R4: wave scaling saturated (38%->73% occ, same dur)
//  R6: subj-tile L2 partitioning -> FETCH 118->35 MB but atomic closes x2.6,
//      WRITE 37->100 MB, dur 56->87 us (atomic-bound). Obj-sort corner wins.
__global__ void hop_merge_kernel(const __half2* __restrict__ xT2,
                                 const float2* __restrict__ rT2,
                                 __half2* __restrict__ outT2,
                                 const uint2* __restrict__ sorted2,
                                 const int* __restrict__ n_hop,
                                 int hop, int n_e, int n_t) {
    int tid = threadIdx.x;
    if (*n_hop < hop) {               // degenerate: identity copy
        long total = (long)n_e * 16;
        for (long i = (long)blockIdx.x * 256 + tid; i < total;
             i += (long)gridDim.x * 256)
            outT2[i] = xT2[i];
        return;
    }
    __shared__ uint2 ent[256];
    int base = blockIdx.x * 256;
    int cnt = min(256, n_t - base);
    ent[tid] = (tid < cnt) ? sorted2[base + tid]
                           : make_uint2(0u, 0xFFFFFFFFu);
    __syncthreads();
    int g = tid >> 4, l = tid & 15;
    int e0 = g * 16;
    int m = min(16, cnt - e0);        // group-uniform
    if (m <= 0) return;

    __half2 xh[16];
#pragma unroll
    for (int j = 0; j < 16; ++j) {    // independent gathers, all in flight
        int s = (int)(ent[e0 + j].x & 0x7FFFF);
        xh[j] = xT2[(size_t)s * 16 + l];
    }

    float a0 = 0.f, a1 = 0.f;
    unsigned cur_o = ent[e0].y;
#pragma unroll
    for (int j = 0; j < 16; ++j) {
        if (j < m) {
            uint2 e = ent[e0 + j];
            float2 rf = rT2[(size_t)(e.x >> 19) * 16 + l];   // L1-resident
            float2 xf = __half22float2(xh[j]);
            if (e.y != cur_o) {                  // uniform within 16-lane group
                unsafeAtomicAdd(&outT2[(size_t)cur_o * 16 + l],
                                __floats2half2_rn(a0, a1));
                a0 = 0.f; a1 = 0.f;
                cur_o = e.y;
            }
            a0 += xf.x * rf.x;
            a1 += xf.y * rf.y;
        }
    }
    unsafeAtomicAdd(&outT2[(size_t)cur_o * 16 + l], __floats2half2_rn(a0, a1));
}

extern "C" void kernel_launch(void* const* d_in, const int* in_sizes, int n_in,
                              void* d_out, int out_size, void* d_ws, size_t ws_size,
                              hipStream_t stream) {
    const float* x    = (const float*)d_in[0];
    const float* q    = (const float*)d_in[1];
    const int*   subj = (const int*)d_in[2];
    const int*   rel  = (const int*)d_in[3];
    const int*   obj  = (const int*)d_in[4];
    const float* W1   = (const float*)d_in[5];
    const float* bb1  = (const float*)d_in[6];
    const float* W2   = (const float*)d_in[7];
    const float* bb2  = (const float*)d_in[8];
    const float* W3   = (const float*)d_in[9];
    const float* bb3  = (const float*)d_in[10];
    const int*   n_hop = (const int*)d_in[11];
    float* out = (float*)d_out;

    const int n_e   = in_sizes[0] / B;        // 500000
    const int n_t   = in_sizes[2];            // 2000000
    const int nb    = (n_e + 255) >> 8;       // 1954 coarse buckets
    const int chunk = (n_t + NBLK - 1) / NBLK;
    const int scanLen = nb * NBLK;            // 500224
    const int snb   = (scanLen + 255) / 256;  // 1954 (<= 2048)

    // ws layout (~102 MB of >=128 MB):
    char* w = (char*)d_ws;
    __half* bufA    = (__half*)w;                     w += 32000000;  // [N_E,B] f16
    __half* bufB    = (__half*)w;                     w += 32000000;  // [N_E,B] f16
    float*  rT      = (float*)w;                      w += 76800;     // 3*[N_R,B]
    int*    hist_bb = (int*)w;                        w += 2097152;   // [nb*NBLK]
    int*    base_bb = (int*)w;                        w += 2097152;   // [nb*NBLK]
    int*    bsums   = (int*)w;                        w += 16384;     // [snb]
    uint2*  packed2 = (uint2*)w;                      w += 16000000;  // [N_T]
    uint2*  sorted2 = (uint2*)w;                                      // [N_T]

    const int rblocks = (NR * B + 255) / 256;
    compute_r3_kernel<<<3 * rblocks, 256, 0, stream>>>(q, W1, bb1, W2, bb2,
                                                       W3, bb3, rT, rblocks);

    const int tblocks = (n_e + 63) / 64;
    transpose_in_kernel<<<tblocks, 256, 0, stream>>>(x, bufA, n_e);

    // --- sort by obj (once) ---
    count_kernel<<<NBLK, CS_THREADS, 0, stream>>>(obj, hist_bb, n_t, nb, chunk);
    block_reduce_kernel<<<snb, 256, 0, stream>>>(hist_bb, bsums, scanLen);
    scan_blocksums_kernel<<<1, 256, 0, stream>>>(bsums, snb);
    scan_apply_kernel<<<snb, 256, 0, stream>>>(hist_bb, bsums, base_bb, scanLen);
    scatter8_kernel<<<NBLK, CS_THREADS, 0, stream>>>(subj, rel, obj, base_bb,
                                                     packed2, n_t, nb, chunk);
    fine_sort_kernel<<<nb, 256, 0, stream>>>(packed2, sorted2, base_bb, n_t, nb);

    // --- 3 flat hops with run-merged atomics ---
    const int hblocks = (n_t + 255) / 256;    // 7813
    const size_t bytes = (size_t)n_e * B * sizeof(__half);

    hipMemsetAsync(bufB, 0, bytes, stream);
    hop_merge_kernel<<<hblocks, 256, 0, stream>>>((const __half2*)bufA,
        (const float2*)(rT + 0 * NR * B), (__half2*)bufB, sorted2, n_hop, 1, n_e, n_t);
    hipMemsetAsync(bufA, 0, bytes, stream);
    hop_merge_kernel<<<hblocks, 256, 0, stream>>>((const __half2*)bufB,
        (const float2*)(rT + 1 * NR * B), (__half2*)bufA, sorted2, n_hop, 2, n_e, n_t);
    hipMemsetAsync(bufB, 0, bytes, stream);
    hop_merge_kernel<<<hblocks, 256, 0, stream>>>((const __half2*)bufA,
        (const float2*)(rT + 2 * NR * B), (__half2*)bufB, sorted2, n_hop, 3, n_e, n_t);

    transpose_out_kernel<<<tblocks, 256, 0, stream>>>(bufB, out, n_e);
}